// Round 8
// baseline (950.557 us; speedup 1.0000x reference)
//
#include <hip/hip_runtime.h>
#include <hip/hip_bf16.h>
#include <math.h>

constexpr int HDIM = 1024;
constexpr int LNUM = 4;
constexpr int DINNER = 2048;
constexpr int KCONV = 4;
constexpr int NB = 2;
constexpr int SLEN = 1024;
constexpr int TOK = NB * SLEN;   // 2048 tokens
constexpr float LNEPS = 1e-5f;

constexpr int NCHUNK = 32;
constexpr int CLEN = SLEN / NCHUNK;   // 32 steps per chunk
constexpr int PROW = 36;              // padded proj row in LDS
constexpr int XPN = 48;               // x_proj rows padded (33 -> 48)
constexpr int XSPLIT = 8;             // split-K factor for xproj (proven round-3)
constexpr int CCH = 32;               // conv s-chunk (register-batched)

typedef __attribute__((ext_vector_type(8))) short short8;
typedef __attribute__((ext_vector_type(4))) float f32x4;

__device__ __forceinline__ __hip_bfloat16 f2bf(float x) { return __float2bfloat16(x); }
__device__ __forceinline__ unsigned short f2bfu(float x) {
    __hip_bfloat16 h = __float2bfloat16(x);
    return *(unsigned short*)&h;
}
__device__ __forceinline__ float sigmoidf_(float x) { return 1.f / (1.f + __expf(-x)); }
__device__ __forceinline__ float siluf_(float x) { return x / (1.f + __expf(-x)); }
__device__ __forceinline__ float softplusf_(float x) { return (x > 20.f) ? x : log1pf(__expf(x)); }

// async global -> LDS, 16 bytes per lane (global_load_lds_dwordx4)
__device__ __forceinline__ void cp16(const void* g, void* l) {
    __builtin_amdgcn_global_load_lds(
        (const __attribute__((address_space(1))) unsigned int*)g,
        (__attribute__((address_space(3))) unsigned int*)l, 16, 0, 0);
}

// ---------------- f32 -> bf16 convert, 4 elems/thread ----------------
__global__ __launch_bounds__(256) void cvt_k(const float* __restrict__ in,
                                             __hip_bfloat16* __restrict__ out, int n4)
{
    const int i = blockIdx.x * 256 + threadIdx.x;
    if (i >= n4) return;
    float4 v = ((const float4*)in)[i];
    ushort4 o;
    o.x = f2bfu(v.x); o.y = f2bfu(v.y); o.z = f2bfu(v.z); o.w = f2bfu(v.w);
    ((ushort4*)out)[i] = o;
}

// x_proj weights: convert [L,33,DINNER] f32 -> [L,XPN,DINNER] bf16 with rows 33..47 zeroed
__global__ __launch_bounds__(256) void cvtwx_k(const float* __restrict__ in,
                                               __hip_bfloat16* __restrict__ out)
{
    const int i = blockIdx.x * 256 + threadIdx.x;          // float4 index
    if (i >= LNUM * XPN * DINNER / 4) return;
    const int e = i * 4;
    const int l = e / (XPN * DINNER);
    const int rem = e - l * XPN * DINNER;
    const int r = rem >> 11;            // row within layer slab (DINNER=2048)
    const int col = rem & (DINNER - 1);
    ushort4 o;
    if (r < 33) {
        float4 v = *(const float4*)&in[(((size_t)l * 33 + r) << 11) + col];
        o.x = f2bfu(v.x); o.y = f2bfu(v.y); o.z = f2bfu(v.z); o.w = f2bfu(v.w);
    } else {
        o.x = o.y = o.z = o.w = 0;
    }
    ((ushort4*)out)[i] = o;
}

// ---------------- LayerNorm (f32 in, vectorized) ----------------
// MODE 0: f32 out; MODE 1: bf16 out
template<int MODE, int D>
__global__ __launch_bounds__(256) void ln_k(
    const float* __restrict__ in, const float* __restrict__ g, const float* __restrict__ b,
    float* __restrict__ outF, __hip_bfloat16* __restrict__ outB)
{
    constexpr int EPT = D / 1024;   // float4s per thread (256 threads)
    const int t = blockIdx.x, tid = threadIdx.x;
    float4 v[EPT];
    float s1 = 0.f, s2 = 0.f;
#pragma unroll
    for (int i = 0; i < EPT; ++i) {
        const int idx = (tid + i * 256) * 4;
        float4 val = *(const float4*)&in[(size_t)t * D + idx];
        v[i] = val;
        s1 += val.x + val.y + val.z + val.w;
        s2 += val.x * val.x + val.y * val.y + val.z * val.z + val.w * val.w;
    }
#pragma unroll
    for (int off = 32; off; off >>= 1) { s1 += __shfl_down(s1, off); s2 += __shfl_down(s2, off); }
    __shared__ float rs[4], rq[4];
    const int w = tid >> 6, lane = tid & 63;
    if (lane == 0) { rs[w] = s1; rq[w] = s2; }
    __syncthreads();
    const float mu = (rs[0] + rs[1] + rs[2] + rs[3]) * (1.f / D);
    const float ms = (rq[0] + rq[1] + rq[2] + rq[3]) * (1.f / D);
    const float var = ms - mu * mu;
    const float rstd = rsqrtf((var > 0.f ? var : 0.f) + LNEPS);
#pragma unroll
    for (int i = 0; i < EPT; ++i) {
        const int idx = (tid + i * 256) * 4;
        const float4 gg = *(const float4*)&g[idx];
        const float4 bb = *(const float4*)&b[idx];
        float4 o;
        o.x = (v[i].x - mu) * rstd * gg.x + bb.x;
        o.y = (v[i].y - mu) * rstd * gg.y + bb.y;
        o.z = (v[i].z - mu) * rstd * gg.z + bb.z;
        o.w = (v[i].w - mu) * rstd * gg.w + bb.w;
        if (MODE == 0) {
            ((float4*)outF)[((size_t)t * D + idx) >> 2] = o;
        } else {
            ushort4 u;
            u.x = f2bfu(o.x); u.y = f2bfu(o.y); u.z = f2bfu(o.z); u.w = f2bfu(o.w);
            ((ushort4*)outB)[((size_t)t * D + idx) >> 2] = u;
        }
    }
}

// ---------------- Fused: y = yA + yB (scan n-split planes), LN, * sigmoid(gate) -> bf16 ----------------
__global__ __launch_bounds__(256) void ynorm_k(
    const float* __restrict__ inA, const float* __restrict__ inB,
    const float* __restrict__ g, const float* __restrict__ b,
    __hip_bfloat16* __restrict__ outB,
    const float* __restrict__ gate, int gstride)
{
    constexpr int D = DINNER;
    constexpr int EPT = D / 1024;
    const int t = blockIdx.x, tid = threadIdx.x;
    float4 v[EPT];
    float s1 = 0.f, s2 = 0.f;
#pragma unroll
    for (int i = 0; i < EPT; ++i) {
        const int idx = (tid + i * 256) * 4;
        float4 a = *(const float4*)&inA[(size_t)t * D + idx];
        float4 c = *(const float4*)&inB[(size_t)t * D + idx];
        float4 val;
        val.x = a.x + c.x; val.y = a.y + c.y; val.z = a.z + c.z; val.w = a.w + c.w;
        v[i] = val;
        s1 += val.x + val.y + val.z + val.w;
        s2 += val.x * val.x + val.y * val.y + val.z * val.z + val.w * val.w;
    }
#pragma unroll
    for (int off = 32; off; off >>= 1) { s1 += __shfl_down(s1, off); s2 += __shfl_down(s2, off); }
    __shared__ float rs[4], rq[4];
    const int w = tid >> 6, lane = tid & 63;
    if (lane == 0) { rs[w] = s1; rq[w] = s2; }
    __syncthreads();
    const float mu = (rs[0] + rs[1] + rs[2] + rs[3]) * (1.f / D);
    const float ms = (rq[0] + rq[1] + rq[2] + rq[3]) * (1.f / D);
    const float var = ms - mu * mu;
    const float rstd = rsqrtf((var > 0.f ? var : 0.f) + LNEPS);
#pragma unroll
    for (int i = 0; i < EPT; ++i) {
        const int idx = (tid + i * 256) * 4;
        const float4 gg = *(const float4*)&g[idx];
        const float4 bb = *(const float4*)&b[idx];
        const float4 gt = *(const float4*)&gate[(size_t)t * gstride + idx];
        ushort4 u;
        u.x = f2bfu(((v[i].x - mu) * rstd * gg.x + bb.x) * sigmoidf_(gt.x));
        u.y = f2bfu(((v[i].y - mu) * rstd * gg.y + bb.y) * sigmoidf_(gt.y));
        u.z = f2bfu(((v[i].z - mu) * rstd * gg.z + bb.z) * sigmoidf_(gt.z));
        u.w = f2bfu(((v[i].w - mu) * rstd * gg.w + bb.w) * sigmoidf_(gt.w));
        ((ushort4*)outB)[((size_t)t * D + idx) >> 2] = u;
    }
}

// ---------------- Fused: x += partial0 + partial1 (out_proj split-K), then LN -> bf16 ----------------
__global__ __launch_bounds__(256) void xcomb_ln_k(
    const float* __restrict__ part, float* __restrict__ x,
    const float* __restrict__ g, const float* __restrict__ b,
    __hip_bfloat16* __restrict__ outB)
{
    const int t = blockIdx.x, tid = threadIdx.x;
    const int idx = tid * 4;
    const size_t off = (size_t)t * HDIM + idx;
    float4 a = *(const float4*)&part[off];
    float4 c = *(const float4*)&part[(size_t)TOK * HDIM + off];
    float4 v = *(const float4*)&x[off];
    v.x += a.x + c.x; v.y += a.y + c.y; v.z += a.z + c.z; v.w += a.w + c.w;
    *(float4*)&x[off] = v;
    float s1 = v.x + v.y + v.z + v.w;
    float s2 = v.x * v.x + v.y * v.y + v.z * v.z + v.w * v.w;
#pragma unroll
    for (int o2 = 32; o2; o2 >>= 1) { s1 += __shfl_down(s1, o2); s2 += __shfl_down(s2, o2); }
    __shared__ float rs[4], rq[4];
    const int w = tid >> 6, lane = tid & 63;
    if (lane == 0) { rs[w] = s1; rq[w] = s2; }
    __syncthreads();
    const float mu = (rs[0] + rs[1] + rs[2] + rs[3]) * (1.f / HDIM);
    const float ms = (rq[0] + rq[1] + rq[2] + rq[3]) * (1.f / HDIM);
    const float var = ms - mu * mu;
    const float rstd = rsqrtf((var > 0.f ? var : 0.f) + LNEPS);
    const float4 gg = *(const float4*)&g[idx];
    const float4 bb = *(const float4*)&b[idx];
    ushort4 u;
    u.x = f2bfu((v.x - mu) * rstd * gg.x + bb.x);
    u.y = f2bfu((v.y - mu) * rstd * gg.y + bb.y);
    u.z = f2bfu((v.z - mu) * rstd * gg.z + bb.z);
    u.w = f2bfu((v.w - mu) * rstd * gg.w + bb.w);
    ((ushort4*)outB)[off >> 2] = u;
}

// Fused final combine: xn = bf16(x + p0 + p1)  (x itself dead afterwards)
__global__ __launch_bounds__(256) void xcomb_cast_k(
    const float* __restrict__ part, const float* __restrict__ x,
    __hip_bfloat16* __restrict__ xn, int n4)
{
    const int i = blockIdx.x * 256 + threadIdx.x;
    if (i >= n4) return;
    float4 a = ((const float4*)part)[i];
    float4 c = ((const float4*)part)[i + n4];
    float4 v = ((const float4*)x)[i];
    v.x += a.x + c.x; v.y += a.y + c.y; v.z += a.z + c.z; v.w += a.w + c.w;
    ushort4 u;
    u.x = f2bfu(v.x); u.y = f2bfu(v.y); u.z = f2bfu(v.z); u.w = f2bfu(v.w);
    ((ushort4*)xn)[i] = u;
}

// ---------------- GEMM (A [M,K] bf16 row-major, B [N,K] bf16 row-major = B^T) ----------------
// Double-buffered async staging.
// EPI 0: Cf[off] = acc
// EPI 1: Cf[z*M*N + off] = acc     (split-K partials, deterministic)
// EPI 2: Cb[off] = bf16(gelu(acc + bias))
// EPI 3: Of[off] = acc + bias[col] + res[off]   (f32 final output)
template<int EPI>
__global__ __launch_bounds__(256) void gemm_bt(
    const unsigned short* __restrict__ A, const unsigned short* __restrict__ B,
    int M, int N, int Kd,
    float* __restrict__ Cf, __hip_bfloat16* __restrict__ Cb,
    const float* __restrict__ bias, const float* __restrict__ res,
    float* __restrict__ Of)
{
    __shared__ __align__(16) unsigned short As[2][128 * 32];
    __shared__ __align__(16) unsigned short Bs[2][128 * 32];
    const int tid = threadIdx.x;
    const int m0 = blockIdx.x * 128, n0 = blockIdx.y * 128;
    const int klen = Kd / (int)gridDim.z;
    const int kstart = (int)blockIdx.z * klen;
    const int nK = klen >> 5;
    const int wave = tid >> 6, lane = tid & 63;
    const int wm = (wave & 1) * 64, wn = (wave >> 1) * 64;
    const int quad = lane >> 4, l16 = lane & 15;
    f32x4 acc[4][4];
#pragma unroll
    for (int i = 0; i < 4; ++i)
#pragma unroll
        for (int j = 0; j < 4; ++j) acc[i][j] = (f32x4){0.f, 0.f, 0.f, 0.f};

    const int r1 = tid >> 2, kc1 = (tid & 3) * 8;
    const int r2 = r1 + 64;

    {
        const int k0 = kstart;
        cp16(&A[(size_t)(m0 + r1) * Kd + k0 + kc1], &As[0][tid * 8]);
        cp16(&A[(size_t)(m0 + r2) * Kd + k0 + kc1], &As[0][(tid + 256) * 8]);
        cp16(&B[(size_t)(n0 + r1) * Kd + k0 + kc1], &Bs[0][tid * 8]);
        cp16(&B[(size_t)(n0 + r2) * Kd + k0 + kc1], &Bs[0][(tid + 256) * 8]);
    }
    for (int kk = 0; kk < nK; ++kk) {
        __syncthreads();   // drains cp16s for buf[kk&1]; protects buf[(kk+1)&1] vs prior reads
        if (kk + 1 < nK) {
            const int k0 = kstart + ((kk + 1) << 5);
            const int nb = (kk + 1) & 1;
            cp16(&A[(size_t)(m0 + r1) * Kd + k0 + kc1], &As[nb][tid * 8]);
            cp16(&A[(size_t)(m0 + r2) * Kd + k0 + kc1], &As[nb][(tid + 256) * 8]);
            cp16(&B[(size_t)(n0 + r1) * Kd + k0 + kc1], &Bs[nb][tid * 8]);
            cp16(&B[(size_t)(n0 + r2) * Kd + k0 + kc1], &Bs[nb][(tid + 256) * 8]);
        }
        const int cb = kk & 1;
        short8 af[4], bfm[4];
#pragma unroll
        for (int i = 0; i < 4; ++i) af[i]  = *(const short8*)&As[cb][(wm + i * 16 + l16) * 32 + quad * 8];
#pragma unroll
        for (int j = 0; j < 4; ++j) bfm[j] = *(const short8*)&Bs[cb][(wn + j * 16 + l16) * 32 + quad * 8];
#pragma unroll
        for (int i = 0; i < 4; ++i)
#pragma unroll
            for (int j = 0; j < 4; ++j)
                acc[i][j] = __builtin_amdgcn_mfma_f32_16x16x32_bf16(af[i], bfm[j], acc[i][j], 0, 0, 0);
    }

    const size_t zoff = (EPI == 1) ? (size_t)blockIdx.z * M * N : 0;
#pragma unroll
    for (int i = 0; i < 4; ++i)
#pragma unroll
        for (int j = 0; j < 4; ++j)
#pragma unroll
            for (int r = 0; r < 4; ++r) {
                const int row = m0 + wm + i * 16 + quad * 4 + r;
                const int col = n0 + wn + j * 16 + l16;
                const size_t off = (size_t)row * N + col;
                float vv = acc[i][j][r];
                if (EPI == 0) {
                    Cf[off] = vv;
                } else if (EPI == 1) {
                    Cf[zoff + off] = vv;
                } else if (EPI == 2) {
                    float z = vv + bias[col];
                    Cb[off] = f2bf(0.5f * z * (1.f + erff(z * 0.70710678118f)));
                } else {
                    Of[off] = vv + bias[col] + res[off];
                }
            }
}

// combine xproj split-K partials: proj[t*33+p] = sum_k ppart[k][t*48+p]
__global__ __launch_bounds__(256) void pcomb_k(const float* __restrict__ ppart,
                                               float* __restrict__ proj)
{
    const int idx = blockIdx.x * 256 + threadIdx.x;
    if (idx >= TOK * 33) return;
    const int t = idx / 33, p2 = idx - t * 33;
    float s = 0.f;
#pragma unroll
    for (int k = 0; k < XSPLIT; ++k)
        s += ppart[(size_t)k * TOK * XPN + (size_t)t * XPN + p2];
    proj[idx] = s;
}

// ---------------- Fused double causal dwconv + silu (register-batched loads) ----------------
__global__ __launch_bounds__(256) void conv2_fused(
    const float* __restrict__ xin, int in_stride,
    const float* __restrict__ cw, const float* __restrict__ cb, int layer,
    float* __restrict__ out, __hip_bfloat16* __restrict__ outb)
{
    const int d = blockIdx.x * 256 + threadIdx.x;
    const int s0 = blockIdx.y * CCH;
    const int b = blockIdx.z;
    float w1k[4], w2k[4];
#pragma unroll
    for (int k = 0; k < 4; ++k) {
        w1k[k] = cw[(((size_t)layer * 2 + 0) * DINNER + d) * KCONV + k];
        w2k[k] = cw[(((size_t)layer * 2 + 1) * DINNER + d) * KCONV + k];
    }
    const float b1 = cb[((size_t)layer * 2 + 0) * DINNER + d];
    const float b2 = cb[((size_t)layer * 2 + 1) * DINNER + d];
    const float* base = xin + (size_t)b * SLEN * in_stride + d;

    float xv[CCH + 6];
#pragma unroll
    for (int i = 0; i < CCH + 6; ++i) {
        const int s = s0 - 6 + i;
        const int sc = (s < 0) ? 0 : s;           // clamped addr: always valid
        xv[i] = base[(size_t)sc * in_stride];
    }
#pragma unroll
    for (int i = 0; i < CCH + 6; ++i) {
        const int s = s0 - 6 + i;
        xv[i] = (s >= 0) ? siluf_(xv[i]) : 0.f;
    }
    float c1[CCH + 3];
#pragma unroll
    for (int i = 0; i < CCH + 3; ++i) {
        const int s = s0 - 3 + i;
        float t = fmaf(w1k[0], xv[i], fmaf(w1k[1], xv[i + 1],
                  fmaf(w1k[2], xv[i + 2], fmaf(w1k[3], xv[i + 3], b1))));
        c1[i] = (s >= 0) ? siluf_(t) : 0.f;
    }
    const size_t obase = (size_t)b * SLEN * DINNER + d;
#pragma unroll
    for (int j = 0; j < CCH; ++j) {
        float t2 = fmaf(w2k[0], c1[j], fmaf(w2k[1], c1[j + 1],
                   fmaf(w2k[2], c1[j + 2], fmaf(w2k[3], c1[j + 3], b2))));
        const float v = siluf_(t2);
        out[obase + (size_t)(s0 + j) * DINNER] = v;
        outb[obase + (size_t)(s0 + j) * DINNER] = f2bf(v);
    }
}

// ---------------- x_proj as split-K MFMA GEMM (double-buffered, partials out) ----------------
__global__ __launch_bounds__(256) void xproj_mfma(
    const unsigned short* __restrict__ A, const unsigned short* __restrict__ B,
    float* __restrict__ ppart)
{
    __shared__ __align__(16) unsigned short As[2][128 * 32];
    __shared__ __align__(16) unsigned short Bs[2][XPN * 32];
    const int tid = threadIdx.x;
    const int m0 = blockIdx.x * 128;
    const int k0base = blockIdx.y * (DINNER / XSPLIT);
    constexpr int nK = (DINNER / XSPLIT) >> 5;
    const int wave = tid >> 6, lane = tid & 63;
    const int wm = wave * 32;
    const int quad = lane >> 4, l16 = lane & 15;
    f32x4 acc[2][3];
#pragma unroll
    for (int i = 0; i < 2; ++i)
#pragma unroll
        for (int j = 0; j < 3; ++j) acc[i][j] = (f32x4){0.f, 0.f, 0.f, 0.f};

    const int r1 = tid >> 2, kc1 = (tid & 3) * 8;
    {
        const int k0 = k0base;
        cp16(&A[(size_t)(m0 + r1) * DINNER + k0 + kc1], &As[0][tid * 8]);
        cp16(&A[(size_t)(m0 + r1 + 64) * DINNER + k0 + kc1], &As[0][(tid + 256) * 8]);
        if (tid < XPN * 4)
            cp16(&B[(size_t)r1 * DINNER + k0 + kc1], &Bs[0][tid * 8]);
    }
    for (int kk = 0; kk < nK; ++kk) {
        __syncthreads();
        if (kk + 1 < nK) {
            const int k0 = k0base + ((kk + 1) << 5);
            const int nb = (kk + 1) & 1;
            cp16(&A[(size_t)(m0 + r1) * DINNER + k0 + kc1], &As[nb][tid * 8]);
            cp16(&A[(size_t)(m0 + r1 + 64) * DINNER + k0 + kc1], &As[nb][(tid + 256) * 8]);
            if (tid < XPN * 4)
                cp16(&B[(size_t)r1 * DINNER + k0 + kc1], &Bs[nb][tid * 8]);
        }
        const int cb = kk & 1;
        short8 af[2], bfm[3];
#pragma unroll
        for (int i = 0; i < 2; ++i) af[i]  = *(const short8*)&As[cb][(wm + i * 16 + l16) * 32 + quad * 8];
#pragma unroll
        for (int j = 0; j < 3; ++j) bfm[j] = *(const short8*)&Bs[cb][(j * 16 + l16) * 32 + quad * 8];
#pragma unroll
        for (int i = 0; i < 2; ++i)
#pragma unroll
            for (int j = 0; j < 3; ++j)
                acc[i][j] = __builtin_amdgcn_mfma_f32_16x16x32_bf16(af[i], bfm[j], acc[i][j], 0, 0, 0);
    }
    float* pp = ppart + (size_t)blockIdx.y * TOK * XPN;
#pragma unroll
    for (int i = 0; i < 2; ++i)
#pragma unroll
        for (int j = 0; j < 3; ++j) {
            const int col = j * 16 + l16;
#pragma unroll
            for (int r = 0; r < 4; ++r) {
                const int row = m0 + wm + i * 16 + quad * 4 + r;
                pp[(size_t)row * XPN + col] = acc[i][j][r];
            }
        }
}

// ---------------- Selective scan: chunked parallel linear recurrence ----------------
// ROUND-0/3 inner structure (proven no-scratch). Do NOT: (a) batch loads into
// register arrays (r1/r2: scratch spills), (b) LDS-stage x (r4: neutral), (c)
// fuse split-K partial sum in here (r5: regressed). NEW (r7): n-split x2 —
// each block handles 8 of the 16 states (blockIdx.x LSB), doubling grid to
// 1024 blocks (4 waves/SIMD) and halving per-thread register state.
__device__ __forceinline__ void load_proj_chunk(float* sp, const float* __restrict__ proj,
                                                int b, int c, int tid)
{
    const float* psrc = proj + ((size_t)b * SLEN + (size_t)c * CLEN) * 33;
    for (int i = tid; i < CLEN * 33; i += 256) {
        int s = i / 33, p = i - s * 33;
        sp[s * PROW + (p == 0 ? 32 : p - 1)] = psrc[i];
    }
}

__global__ __launch_bounds__(256) void scan_partA(
    const float* __restrict__ proj, const float* __restrict__ xin,
    const float* __restrict__ dtw, const float* __restrict__ dtb, int layer,
    float* __restrict__ hloc, float* __restrict__ cumA_g)
{
    __shared__ __align__(16) float sp[CLEN * PROW];
    const int tid = threadIdx.x;
    const int ns = blockIdx.x & 1;                 // state half: n = ns*8 + j
    const int d = (blockIdx.x >> 1) * 256 + tid;
    const int c = blockIdx.y, b = blockIdx.z;
    load_proj_chunk(sp, proj, b, c, tid);
    const float w_ = dtw[(size_t)layer * DINNER + d];
    const float bb = dtb[(size_t)layer * DINNER + d];
    const float n0f = (float)(ns * 8);
    __syncthreads();
    float h[8], ca[8];
#pragma unroll
    for (int j = 0; j < 8; ++j) { h[j] = 0.f; ca[j] = 1.f; }
    const float* xrow = xin + ((size_t)b * SLEN + (size_t)c * CLEN) * DINNER + d;
    float xt_next = xrow[0];
    for (int s = 0; s < CLEN; ++s) {
        const float xt = xt_next;
        if (s + 1 < CLEN) xt_next = xrow[(size_t)(s + 1) * DINNER];
        const float* row = &sp[s * PROW] + ns * 8;
        const float dt = softplusf_(fmaf(sp[s * PROW + 32], w_, bb));
        const float u = dt * xt;
#pragma unroll
        for (int j = 0; j < 8; ++j) {
            const float a = fmaf(dt, -(n0f + (float)(j + 1)), 1.f);
            h[j] = fmaf(h[j], a, u * row[j]);
            ca[j] *= a;
        }
    }
    const size_t base = (((size_t)b * NCHUNK + c) * 16 + ns * 8) * DINNER + d;
#pragma unroll
    for (int j = 0; j < 8; ++j) {
        hloc[base + (size_t)j * DINNER] = h[j];
        cumA_g[base + (size_t)j * DINNER] = ca[j];
    }
}

__global__ __launch_bounds__(256) void scan_combine(
    const float* __restrict__ hloc, const float* __restrict__ cumA_g,
    float* __restrict__ hin)
{
    const int idx = blockIdx.x * 256 + threadIdx.x;  // (b, n, d)
    const int d = idx & (DINNER - 1);
    const int n = (idx >> 11) & 15;
    const int b = idx >> 15;
    float h = 0.f;
    for (int c = 0; c < NCHUNK; ++c) {
        const size_t off = (((size_t)b * NCHUNK + c) * 16 + n) * DINNER + d;
        hin[off] = h;
        h = fmaf(cumA_g[off], h, hloc[off]);
    }
}

// n-split partC: half ns computes yp over its 8 states; ns=0 adds xt*D and
// writes plane yA, ns=1 writes plane yB. ynorm_k sums the planes.
__global__ __launch_bounds__(256) void scan_partC(
    const float* __restrict__ proj, const float* __restrict__ xin,
    const float* __restrict__ dtw, const float* __restrict__ dtb,
    const float* __restrict__ Dp, int layer,
    const float* __restrict__ hin, float* __restrict__ yA, float* __restrict__ yB)
{
    __shared__ __align__(16) float sp[CLEN * PROW];
    const int tid = threadIdx.x;
    const int ns = blockIdx.x & 1;
    const int d = (blockIdx.x >> 1) * 256 + tid;
    const int c = blockIdx.y, b = blockIdx.z;
    load_proj_chunk(sp, proj, b, c, tid);
    const float w_ = dtw[(size_t)layer * DINNER + d];
    const float bb = dtb[(size_t)layer * DINNER + d];
    const float dmul = ns ? 0.f : Dp[(size_t)layer * DINNER + d];
    const float n0f = (float)(ns * 8);
    __syncthreads();
    float h[8];
    const size_t base = (((size_t)b * NCHUNK + c) * 16 + ns * 8) * DINNER + d;
#pragma unroll
    for (int j = 0; j < 8; ++j) h[j] = hin[base + (size_t)j * DINNER];
    const float* xrow = xin + ((size_t)b * SLEN + (size_t)c * CLEN) * DINNER + d;
    float* yrow = (ns ? yB : yA) + ((size_t)b * SLEN + (size_t)c * CLEN) * DINNER + d;
    float xt_next = xrow[0];
    for (int s = 0; s < CLEN; ++s) {
        const float xt = xt_next;
        if (s + 1 < CLEN) xt_next = xrow[(size_t)(s + 1) * DINNER];
        const float* row = &sp[s * PROW] + ns * 8;
        const float dt = softplusf_(fmaf(sp[s * PROW + 32], w_, bb));
        const float u = dt * xt;
        float yp = 0.f;
#pragma unroll
        for (int j = 0; j < 8; ++j) {
            const float a = fmaf(dt, -(n0f + (float)(j + 1)), 1.f);
            h[j] = fmaf(h[j], a, u * row[j]);
            yp = fmaf(h[j], row[16 + j], yp);
        }
        yrow[(size_t)s * DINNER] = yp + xt * dmul;
    }
}

extern "C" void kernel_launch(void* const* d_in, const int* in_sizes, int n_in,
                              void* d_out, int out_size, void* d_ws, size_t ws_size,
                              hipStream_t stream)
{
    (void)in_sizes; (void)n_in; (void)out_size;
    const float* hs   = (const float*)d_in[0];
    const float* ing  = (const float*)d_in[1];
    const float* inb  = (const float*)d_in[2];
    const float* lng  = (const float*)d_in[3];
    const float* lnb  = (const float*)d_in[4];
    const float* ipw  = (const float*)d_in[5];
    const float* cw   = (const float*)d_in[6];
    const float* cbp  = (const float*)d_in[7];
    const float* xpw  = (const float*)d_in[8];
    const float* dtw  = (const float*)d_in[9];
    const float* dtb  = (const float*)d_in[10];
    const float* Dp   = (const float*)d_in[11];
    const float* mlg  = (const float*)d_in[12];
    const float* mlb  = (const float*)d_in[13];
    const float* opw  = (const float*)d_in[14];
    const float* w1f  = (const float*)d_in[15];
    const float* b1f  = (const float*)d_in[16];
    const float* w2f  = (const float*)d_in[17];
    const float* b2f  = (const float*)d_in[18];

    // ---- workspace carve ----
    char* p = (char*)d_ws;
    float* x   = (float*)p; p += (size_t)TOK * HDIM * 4;
    float* xr  = (float*)p; p += (size_t)TOK * 2 * DINNER * 4;
    float* c2  = (float*)p; p += (size_t)TOK * DINNER * 4;
    float* yb  = (float*)p; p += (size_t)TOK * DINNER * 4;
    float* yb2 = (float*)p; p += (size_t)TOK * DINNER * 4;                   // n-split plane B
    float* proj= (float*)p; p += ((size_t)TOK * 33 * 4 + 255) & ~(size_t)255;
    float* hin = (float*)p; p += (size_t)NB * NCHUNK * 16 * DINNER * 4;      // 8.4 MB
    float* ppart=(float*)p; p += (size_t)XSPLIT * TOK * XPN * 4;             // 3.1 MB
    __hip_bfloat16* xn  = (__hip_bfloat16*)p; p += (size_t)TOK * HDIM * 2;
    __hip_bfloat16* y2  = (__hip_bfloat16*)p; p += (size_t)TOK * DINNER * 2;
    __hip_bfloat16* c2b = (__hip_bfloat16*)p; p += (size_t)TOK * DINNER * 2; // 8 MB
    __hip_bfloat16* wx  = (__hip_bfloat16*)p; p += (size_t)LNUM * XPN * DINNER * 2;
    __hip_bfloat16* t1 = (__hip_bfloat16*)xr;  // alias: xr dead after layer loop
    float* hloc = yb;                           // alias: yb region, dead before partC writes
    float* cumA = yb + (size_t)NB * NCHUNK * 16 * DINNER;
    float* opart = c2;                          // alias: c2 dead after scan_partC

    const size_t IPL = (size_t)2 * DINNER * HDIM;
    const size_t OPL = (size_t)HDIM * DINNER;
    const size_t MLPW = (size_t)HDIM * HDIM;

    size_t used = (size_t)(p - (char*)d_ws);
    const bool bulk = (used + (IPL * LNUM + OPL * LNUM + 2 * MLPW) * 2) <= ws_size;

    __hip_bfloat16 *wi[LNUM], *wo[LNUM], *w1, *w2;
    if (bulk) {
        for (int l = 0; l < LNUM; ++l) { wi[l] = (__hip_bfloat16*)p; p += IPL * 2; }
        for (int l = 0; l < LNUM; ++l) { wo[l] = (__hip_bfloat16*)p; p += OPL * 2; }
        w1 = (__hip_bfloat16*)p; p += MLPW * 2;
        w2 = (__hip_bfloat16*)p; p += MLPW * 2;
    } else {
        __hip_bfloat16* slotA = (__hip_bfloat16*)p; p += IPL * 2;
        __hip_bfloat16* slotB = (__hip_bfloat16*)p; p += OPL * 2;
        for (int l = 0; l < LNUM; ++l) { wi[l] = slotA; wo[l] = slotB; }
        w1 = slotA; w2 = slotB;
    }

    // x_proj weights: convert + zero-pad to [L, 48, DINNER]
    cvtwx_k<<<(LNUM * XPN * DINNER / 4 + 255) / 256, 256, 0, stream>>>(xpw, wx);

    if (bulk) {
        cvt_k<<<(int)(IPL * LNUM / 4 / 256), 256, 0, stream>>>(ipw, wi[0], (int)(IPL * LNUM / 4));
        cvt_k<<<(int)(OPL * LNUM / 4 / 256), 256, 0, stream>>>(opw, wo[0], (int)(OPL * LNUM / 4));
        cvt_k<<<(int)(MLPW / 4 / 256), 256, 0, stream>>>(w1f, w1, (int)(MLPW / 4));
        cvt_k<<<(int)(MLPW / 4 / 256), 256, 0, stream>>>(w2f, w2, (int)(MLPW / 4));
    }

    // x = layernorm(hidden_states); then xn = bf16(LN_0(x)) for layer 0
    ln_k<0, HDIM><<<TOK, 256, 0, stream>>>(hs, ing, inb, x, nullptr);
    ln_k<1, HDIM><<<TOK, 256, 0, stream>>>(x, lng, lnb, nullptr, xn);

    for (int l = 0; l < LNUM; ++l) {
        if (!bulk)
            cvt_k<<<(int)(IPL / 4 / 256), 256, 0, stream>>>(ipw + (size_t)l * IPL, wi[l], (int)(IPL / 4));
        gemm_bt<0><<<dim3(TOK / 128, (2 * DINNER) / 128), 256, 0, stream>>>(
            (const unsigned short*)xn, (const unsigned short*)wi[l],
            TOK, 2 * DINNER, HDIM, xr, nullptr, nullptr, nullptr, nullptr);

        conv2_fused<<<dim3(DINNER / 256, SLEN / CCH, NB), 256, 0, stream>>>(
            xr, 2 * DINNER, cw, cbp, l, c2, c2b);

        xproj_mfma<<<dim3(TOK / 128, XSPLIT), 256, 0, stream>>>(
            (const unsigned short*)c2b, (const unsigned short*)(wx + (size_t)l * XPN * DINNER), ppart);
        pcomb_k<<<(TOK * 33 + 255) / 256, 256, 0, stream>>>(ppart, proj);

        scan_partA<<<dim3(DINNER / 256 * 2, NCHUNK, NB), 256, 0, stream>>>(
            proj, c2, dtw, dtb, l, hloc, cumA);
        scan_combine<<<(NB * 16 * DINNER) / 256, 256, 0, stream>>>(hloc, cumA, hin);
        scan_partC<<<dim3(DINNER / 256 * 2, NCHUNK, NB), 256, 0, stream>>>(
            proj, c2, dtw, dtb, Dp, l, hin, yb, yb2);

        ynorm_k<<<TOK, 256, 0, stream>>>(yb, yb2, mlg + (size_t)l * DINNER, mlb + (size_t)l * DINNER,
                                         y2, xr + DINNER, 2 * DINNER);

        if (!bulk)
            cvt_k<<<(int)(OPL / 4 / 256), 256, 0, stream>>>(opw + (size_t)l * OPL, wo[l], (int)(OPL / 4));
        // out_proj split-K=2 -> deterministic partials (c2 is dead now)
        gemm_bt<1><<<dim3(TOK / 128, HDIM / 128, 2), 256, 0, stream>>>(
            (const unsigned short*)y2, (const unsigned short*)wo[l],
            TOK, HDIM, DINNER, opart, nullptr, nullptr, nullptr, nullptr);
        if (l + 1 < LNUM) {
            // fused: x += partials; xn = bf16(LN_{l+1}(x))
            xcomb_ln_k<<<TOK, 256, 0, stream>>>(opart, x,
                lng + (size_t)(l + 1) * HDIM, lnb + (size_t)(l + 1) * HDIM, xn);
        } else {
            // fused final: xn = bf16(x + partials)
            xcomb_cast_k<<<(TOK * HDIM / 4 + 255) / 256, 256, 0, stream>>>(
                opart, x, xn, TOK * HDIM / 4);
        }
    }

    // MLP: out = gelu(x @ op1^T + b1) @ op2^T + b2 + hidden_states
    if (!bulk) {
        cvt_k<<<(int)(MLPW / 4 / 256), 256, 0, stream>>>(w1f, w1, (int)(MLPW / 4));
        cvt_k<<<(int)(MLPW / 4 / 256), 256, 0, stream>>>(w2f, w2, (int)(MLPW / 4));
    }
    gemm_bt<2><<<dim3(TOK / 128, HDIM / 128), 256, 0, stream>>>(
        (const unsigned short*)xn, (const unsigned short*)w1,
        TOK, HDIM, HDIM, nullptr, t1, b1f, nullptr, nullptr);
    gemm_bt<3><<<dim3(TOK / 128, HDIM / 128), 256, 0, stream>>>(
        (const unsigned short*)t1, (const unsigned short*)w2,
        TOK, HDIM, HDIM, nullptr, nullptr, b2f, hs, (float*)d_out);
}

// Round 9
// 828.566 us; speedup vs baseline: 1.1472x; 1.1472x over previous
//
#include <hip/hip_runtime.h>
#include <hip/hip_bf16.h>
#include <math.h>

constexpr int HDIM = 1024;
constexpr int LNUM = 4;
constexpr int DINNER = 2048;
constexpr int KCONV = 4;
constexpr int NB = 2;
constexpr int SLEN = 1024;
constexpr int TOK = NB * SLEN;   // 2048 tokens
constexpr float LNEPS = 1e-5f;

constexpr int NCHUNK = 32;
constexpr int CLEN = SLEN / NCHUNK;   // 32 steps per chunk
constexpr int PROW = 36;              // padded proj row in LDS
constexpr int XPN = 48;               // x_proj rows padded (33 -> 48)
constexpr int XSPLIT = 8;             // split-K factor for xproj (proven round-3)
constexpr int CCH = 32;               // conv s-chunk (register-batched)

typedef __attribute__((ext_vector_type(8))) short short8;
typedef __attribute__((ext_vector_type(4))) float f32x4;

__device__ __forceinline__ __hip_bfloat16 f2bf(float x) { return __float2bfloat16(x); }
__device__ __forceinline__ unsigned short f2bfu(float x) {
    __hip_bfloat16 h = __float2bfloat16(x);
    return *(unsigned short*)&h;
}
__device__ __forceinline__ float sigmoidf_(float x) { return 1.f / (1.f + __expf(-x)); }
__device__ __forceinline__ float siluf_(float x) { return x / (1.f + __expf(-x)); }
__device__ __forceinline__ float softplusf_(float x) { return (x > 20.f) ? x : log1pf(__expf(x)); }

// async global -> LDS, 16 bytes per lane (global_load_lds_dwordx4)
__device__ __forceinline__ void cp16(const void* g, void* l) {
    __builtin_amdgcn_global_load_lds(
        (const __attribute__((address_space(1))) unsigned int*)g,
        (__attribute__((address_space(3))) unsigned int*)l, 16, 0, 0);
}

// ---------------- f32 -> bf16 convert, 4 elems/thread ----------------
__global__ __launch_bounds__(256) void cvt_k(const float* __restrict__ in,
                                             __hip_bfloat16* __restrict__ out, int n4)
{
    const int i = blockIdx.x * 256 + threadIdx.x;
    if (i >= n4) return;
    float4 v = ((const float4*)in)[i];
    ushort4 o;
    o.x = f2bfu(v.x); o.y = f2bfu(v.y); o.z = f2bfu(v.z); o.w = f2bfu(v.w);
    ((ushort4*)out)[i] = o;
}

// x_proj weights: convert [L,33,DINNER] f32 -> [L,XPN,DINNER] bf16 with rows 33..47 zeroed
__global__ __launch_bounds__(256) void cvtwx_k(const float* __restrict__ in,
                                               __hip_bfloat16* __restrict__ out)
{
    const int i = blockIdx.x * 256 + threadIdx.x;          // float4 index
    if (i >= LNUM * XPN * DINNER / 4) return;
    const int e = i * 4;
    const int l = e / (XPN * DINNER);
    const int rem = e - l * XPN * DINNER;
    const int r = rem >> 11;            // row within layer slab (DINNER=2048)
    const int col = rem & (DINNER - 1);
    ushort4 o;
    if (r < 33) {
        float4 v = *(const float4*)&in[(((size_t)l * 33 + r) << 11) + col];
        o.x = f2bfu(v.x); o.y = f2bfu(v.y); o.z = f2bfu(v.z); o.w = f2bfu(v.w);
    } else {
        o.x = o.y = o.z = o.w = 0;
    }
    ((ushort4*)out)[i] = o;
}

// ---------------- LayerNorm (f32 in, vectorized) ----------------
// MODE 0: f32 out; MODE 1: bf16 out; MODE 2: bf16 out * sigmoid(gate)
template<int MODE, int D>
__global__ __launch_bounds__(256) void ln_k(
    const float* __restrict__ in, const float* __restrict__ g, const float* __restrict__ b,
    float* __restrict__ outF, __hip_bfloat16* __restrict__ outB,
    const float* __restrict__ gate, int gstride)
{
    constexpr int EPT = D / 1024;   // float4s per thread (256 threads)
    const int t = blockIdx.x, tid = threadIdx.x;
    float4 v[EPT];
    float s1 = 0.f, s2 = 0.f;
#pragma unroll
    for (int i = 0; i < EPT; ++i) {
        const int idx = (tid + i * 256) * 4;
        float4 val = *(const float4*)&in[(size_t)t * D + idx];
        v[i] = val;
        s1 += val.x + val.y + val.z + val.w;
        s2 += val.x * val.x + val.y * val.y + val.z * val.z + val.w * val.w;
    }
#pragma unroll
    for (int off = 32; off; off >>= 1) { s1 += __shfl_down(s1, off); s2 += __shfl_down(s2, off); }
    __shared__ float rs[4], rq[4];
    const int w = tid >> 6, lane = tid & 63;
    if (lane == 0) { rs[w] = s1; rq[w] = s2; }
    __syncthreads();
    const float mu = (rs[0] + rs[1] + rs[2] + rs[3]) * (1.f / D);
    const float ms = (rq[0] + rq[1] + rq[2] + rq[3]) * (1.f / D);
    const float var = ms - mu * mu;
    const float rstd = rsqrtf((var > 0.f ? var : 0.f) + LNEPS);
#pragma unroll
    for (int i = 0; i < EPT; ++i) {
        const int idx = (tid + i * 256) * 4;
        const float4 gg = *(const float4*)&g[idx];
        const float4 bb = *(const float4*)&b[idx];
        float4 o;
        o.x = (v[i].x - mu) * rstd * gg.x + bb.x;
        o.y = (v[i].y - mu) * rstd * gg.y + bb.y;
        o.z = (v[i].z - mu) * rstd * gg.z + bb.z;
        o.w = (v[i].w - mu) * rstd * gg.w + bb.w;
        if (MODE == 2) {
            const float4 gt = *(const float4*)&gate[(size_t)t * gstride + idx];
            o.x *= sigmoidf_(gt.x); o.y *= sigmoidf_(gt.y);
            o.z *= sigmoidf_(gt.z); o.w *= sigmoidf_(gt.w);
        }
        if (MODE == 0) {
            ((float4*)outF)[((size_t)t * D + idx) >> 2] = o;
        } else {
            ushort4 u;
            u.x = f2bfu(o.x); u.y = f2bfu(o.y); u.z = f2bfu(o.z); u.w = f2bfu(o.w);
            ((ushort4*)outB)[((size_t)t * D + idx) >> 2] = u;
        }
    }
}

// ---------------- Fused: x += partial0 + partial1 (out_proj split-K), then LN -> bf16 ----------------
__global__ __launch_bounds__(256) void xcomb_ln_k(
    const float* __restrict__ part, float* __restrict__ x,
    const float* __restrict__ g, const float* __restrict__ b,
    __hip_bfloat16* __restrict__ outB)
{
    const int t = blockIdx.x, tid = threadIdx.x;
    const int idx = tid * 4;
    const size_t off = (size_t)t * HDIM + idx;
    float4 a = *(const float4*)&part[off];
    float4 c = *(const float4*)&part[(size_t)TOK * HDIM + off];
    float4 v = *(const float4*)&x[off];
    v.x += a.x + c.x; v.y += a.y + c.y; v.z += a.z + c.z; v.w += a.w + c.w;
    *(float4*)&x[off] = v;
    float s1 = v.x + v.y + v.z + v.w;
    float s2 = v.x * v.x + v.y * v.y + v.z * v.z + v.w * v.w;
#pragma unroll
    for (int o2 = 32; o2; o2 >>= 1) { s1 += __shfl_down(s1, o2); s2 += __shfl_down(s2, o2); }
    __shared__ float rs[4], rq[4];
    const int w = tid >> 6, lane = tid & 63;
    if (lane == 0) { rs[w] = s1; rq[w] = s2; }
    __syncthreads();
    const float mu = (rs[0] + rs[1] + rs[2] + rs[3]) * (1.f / HDIM);
    const float ms = (rq[0] + rq[1] + rq[2] + rq[3]) * (1.f / HDIM);
    const float var = ms - mu * mu;
    const float rstd = rsqrtf((var > 0.f ? var : 0.f) + LNEPS);
    const float4 gg = *(const float4*)&g[idx];
    const float4 bb = *(const float4*)&b[idx];
    ushort4 u;
    u.x = f2bfu((v.x - mu) * rstd * gg.x + bb.x);
    u.y = f2bfu((v.y - mu) * rstd * gg.y + bb.y);
    u.z = f2bfu((v.z - mu) * rstd * gg.z + bb.z);
    u.w = f2bfu((v.w - mu) * rstd * gg.w + bb.w);
    ((ushort4*)outB)[off >> 2] = u;
}

// Fused final combine: xn = bf16(x + p0 + p1)  (x itself dead afterwards)
__global__ __launch_bounds__(256) void xcomb_cast_k(
    const float* __restrict__ part, const float* __restrict__ x,
    __hip_bfloat16* __restrict__ xn, int n4)
{
    const int i = blockIdx.x * 256 + threadIdx.x;
    if (i >= n4) return;
    float4 a = ((const float4*)part)[i];
    float4 c = ((const float4*)part)[i + n4];
    float4 v = ((const float4*)x)[i];
    v.x += a.x + c.x; v.y += a.y + c.y; v.z += a.z + c.z; v.w += a.w + c.w;
    ushort4 u;
    u.x = f2bfu(v.x); u.y = f2bfu(v.y); u.z = f2bfu(v.z); u.w = f2bfu(v.w);
    ((ushort4*)xn)[i] = u;
}

// ---------------- GEMM (A [M,K] bf16 row-major, B [N,K] bf16 row-major = B^T) ----------------
// Double-buffered async staging.
// EPI 0: Cf[off] = acc
// EPI 1: Cf[z*M*N + off] = acc     (split-K partials, deterministic)
// EPI 2: Cb[off] = bf16(gelu(acc + bias))
// EPI 3: Of[off] = acc + bias[col] + res[off]   (f32 final output)
template<int EPI>
__global__ __launch_bounds__(256) void gemm_bt(
    const unsigned short* __restrict__ A, const unsigned short* __restrict__ B,
    int M, int N, int Kd,
    float* __restrict__ Cf, __hip_bfloat16* __restrict__ Cb,
    const float* __restrict__ bias, const float* __restrict__ res,
    float* __restrict__ Of)
{
    __shared__ __align__(16) unsigned short As[2][128 * 32];
    __shared__ __align__(16) unsigned short Bs[2][128 * 32];
    const int tid = threadIdx.x;
    const int m0 = blockIdx.x * 128, n0 = blockIdx.y * 128;
    const int klen = Kd / (int)gridDim.z;
    const int kstart = (int)blockIdx.z * klen;
    const int nK = klen >> 5;
    const int wave = tid >> 6, lane = tid & 63;
    const int wm = (wave & 1) * 64, wn = (wave >> 1) * 64;
    const int quad = lane >> 4, l16 = lane & 15;
    f32x4 acc[4][4];
#pragma unroll
    for (int i = 0; i < 4; ++i)
#pragma unroll
        for (int j = 0; j < 4; ++j) acc[i][j] = (f32x4){0.f, 0.f, 0.f, 0.f};

    const int r1 = tid >> 2, kc1 = (tid & 3) * 8;
    const int r2 = r1 + 64;

    {
        const int k0 = kstart;
        cp16(&A[(size_t)(m0 + r1) * Kd + k0 + kc1], &As[0][tid * 8]);
        cp16(&A[(size_t)(m0 + r2) * Kd + k0 + kc1], &As[0][(tid + 256) * 8]);
        cp16(&B[(size_t)(n0 + r1) * Kd + k0 + kc1], &Bs[0][tid * 8]);
        cp16(&B[(size_t)(n0 + r2) * Kd + k0 + kc1], &Bs[0][(tid + 256) * 8]);
    }
    for (int kk = 0; kk < nK; ++kk) {
        __syncthreads();   // drains cp16s for buf[kk&1]; protects buf[(kk+1)&1] vs prior reads
        if (kk + 1 < nK) {
            const int k0 = kstart + ((kk + 1) << 5);
            const int nb = (kk + 1) & 1;
            cp16(&A[(size_t)(m0 + r1) * Kd + k0 + kc1], &As[nb][tid * 8]);
            cp16(&A[(size_t)(m0 + r2) * Kd + k0 + kc1], &As[nb][(tid + 256) * 8]);
            cp16(&B[(size_t)(n0 + r1) * Kd + k0 + kc1], &Bs[nb][tid * 8]);
            cp16(&B[(size_t)(n0 + r2) * Kd + k0 + kc1], &Bs[nb][(tid + 256) * 8]);
        }
        const int cb = kk & 1;
        short8 af[4], bfm[4];
#pragma unroll
        for (int i = 0; i < 4; ++i) af[i]  = *(const short8*)&As[cb][(wm + i * 16 + l16) * 32 + quad * 8];
#pragma unroll
        for (int j = 0; j < 4; ++j) bfm[j] = *(const short8*)&Bs[cb][(wn + j * 16 + l16) * 32 + quad * 8];
#pragma unroll
        for (int i = 0; i < 4; ++i)
#pragma unroll
            for (int j = 0; j < 4; ++j)
                acc[i][j] = __builtin_amdgcn_mfma_f32_16x16x32_bf16(af[i], bfm[j], acc[i][j], 0, 0, 0);
    }

    const size_t zoff = (EPI == 1) ? (size_t)blockIdx.z * M * N : 0;
#pragma unroll
    for (int i = 0; i < 4; ++i)
#pragma unroll
        for (int j = 0; j < 4; ++j)
#pragma unroll
            for (int r = 0; r < 4; ++r) {
                const int row = m0 + wm + i * 16 + quad * 4 + r;
                const int col = n0 + wn + j * 16 + l16;
                const size_t off = (size_t)row * N + col;
                float vv = acc[i][j][r];
                if (EPI == 0) {
                    Cf[off] = vv;
                } else if (EPI == 1) {
                    Cf[zoff + off] = vv;
                } else if (EPI == 2) {
                    float z = vv + bias[col];
                    Cb[off] = f2bf(0.5f * z * (1.f + erff(z * 0.70710678118f)));
                } else {
                    Of[off] = vv + bias[col] + res[off];
                }
            }
}

// combine xproj split-K partials: proj[t*33+p] = sum_k ppart[k][t*48+p]
__global__ __launch_bounds__(256) void pcomb_k(const float* __restrict__ ppart,
                                               float* __restrict__ proj)
{
    const int idx = blockIdx.x * 256 + threadIdx.x;
    if (idx >= TOK * 33) return;
    const int t = idx / 33, p2 = idx - t * 33;
    float s = 0.f;
#pragma unroll
    for (int k = 0; k < XSPLIT; ++k)
        s += ppart[(size_t)k * TOK * XPN + (size_t)t * XPN + p2];
    proj[idx] = s;
}

// ---------------- dt precompute: dtbuf[t][d] = softplus(dt_raw[t]*w[d]+b[d]) ----------------
// Hoists the per-step softplus/log1pf (expensive libm expansion) OUT of the scan
// recurrence, where it was computed redundantly in partA AND partC (r8 evidence:
// duplicating dt work made scans VALU-bound at 70% VALUBusy). Same fmaf+softplus
// ops -> bit-identical numerics.
__global__ __launch_bounds__(256) void dtprep_k(
    const float* __restrict__ proj, const float* __restrict__ dtw,
    const float* __restrict__ dtb, int layer, float* __restrict__ dtbuf)
{
    const int i = blockIdx.x * 256 + threadIdx.x;          // float4 index
    if (i >= TOK * DINNER / 4) return;
    const int t = i / (DINNER / 4);
    const int dcol = (i - t * (DINNER / 4)) * 4;
    const float draw = proj[(size_t)t * 33];               // dt_raw
    const float4 w4 = *(const float4*)&dtw[(size_t)layer * DINNER + dcol];
    const float4 b4 = *(const float4*)&dtb[(size_t)layer * DINNER + dcol];
    float4 o;
    o.x = softplusf_(fmaf(draw, w4.x, b4.x));
    o.y = softplusf_(fmaf(draw, w4.y, b4.y));
    o.z = softplusf_(fmaf(draw, w4.z, b4.z));
    o.w = softplusf_(fmaf(draw, w4.w, b4.w));
    ((float4*)dtbuf)[i] = o;
}

// ---------------- Fused double causal dwconv + silu (register-batched loads) ----------------
__global__ __launch_bounds__(256) void conv2_fused(
    const float* __restrict__ xin, int in_stride,
    const float* __restrict__ cw, const float* __restrict__ cb, int layer,
    float* __restrict__ out, __hip_bfloat16* __restrict__ outb)
{
    const int d = blockIdx.x * 256 + threadIdx.x;
    const int s0 = blockIdx.y * CCH;
    const int b = blockIdx.z;
    float w1k[4], w2k[4];
#pragma unroll
    for (int k = 0; k < 4; ++k) {
        w1k[k] = cw[(((size_t)layer * 2 + 0) * DINNER + d) * KCONV + k];
        w2k[k] = cw[(((size_t)layer * 2 + 1) * DINNER + d) * KCONV + k];
    }
    const float b1 = cb[((size_t)layer * 2 + 0) * DINNER + d];
    const float b2 = cb[((size_t)layer * 2 + 1) * DINNER + d];
    const float* base = xin + (size_t)b * SLEN * in_stride + d;

    float xv[CCH + 6];
#pragma unroll
    for (int i = 0; i < CCH + 6; ++i) {
        const int s = s0 - 6 + i;
        const int sc = (s < 0) ? 0 : s;           // clamped addr: always valid
        xv[i] = base[(size_t)sc * in_stride];
    }
#pragma unroll
    for (int i = 0; i < CCH + 6; ++i) {
        const int s = s0 - 6 + i;
        xv[i] = (s >= 0) ? siluf_(xv[i]) : 0.f;
    }
    float c1[CCH + 3];
#pragma unroll
    for (int i = 0; i < CCH + 3; ++i) {
        const int s = s0 - 3 + i;
        float t = fmaf(w1k[0], xv[i], fmaf(w1k[1], xv[i + 1],
                  fmaf(w1k[2], xv[i + 2], fmaf(w1k[3], xv[i + 3], b1))));
        c1[i] = (s >= 0) ? siluf_(t) : 0.f;
    }
    const size_t obase = (size_t)b * SLEN * DINNER + d;
#pragma unroll
    for (int j = 0; j < CCH; ++j) {
        float t2 = fmaf(w2k[0], c1[j], fmaf(w2k[1], c1[j + 1],
                   fmaf(w2k[2], c1[j + 2], fmaf(w2k[3], c1[j + 3], b2))));
        const float v = siluf_(t2);
        out[obase + (size_t)(s0 + j) * DINNER] = v;
        outb[obase + (size_t)(s0 + j) * DINNER] = f2bf(v);
    }
}

// ---------------- x_proj as split-K MFMA GEMM (double-buffered, partials out) ----------------
__global__ __launch_bounds__(256) void xproj_mfma(
    const unsigned short* __restrict__ A, const unsigned short* __restrict__ B,
    float* __restrict__ ppart)
{
    __shared__ __align__(16) unsigned short As[2][128 * 32];
    __shared__ __align__(16) unsigned short Bs[2][XPN * 32];
    const int tid = threadIdx.x;
    const int m0 = blockIdx.x * 128;
    const int k0base = blockIdx.y * (DINNER / XSPLIT);
    constexpr int nK = (DINNER / XSPLIT) >> 5;
    const int wave = tid >> 6, lane = tid & 63;
    const int wm = wave * 32;
    const int quad = lane >> 4, l16 = lane & 15;
    f32x4 acc[2][3];
#pragma unroll
    for (int i = 0; i < 2; ++i)
#pragma unroll
        for (int j = 0; j < 3; ++j) acc[i][j] = (f32x4){0.f, 0.f, 0.f, 0.f};

    const int r1 = tid >> 2, kc1 = (tid & 3) * 8;
    {
        const int k0 = k0base;
        cp16(&A[(size_t)(m0 + r1) * DINNER + k0 + kc1], &As[0][tid * 8]);
        cp16(&A[(size_t)(m0 + r1 + 64) * DINNER + k0 + kc1], &As[0][(tid + 256) * 8]);
        if (tid < XPN * 4)
            cp16(&B[(size_t)r1 * DINNER + k0 + kc1], &Bs[0][tid * 8]);
    }
    for (int kk = 0; kk < nK; ++kk) {
        __syncthreads();
        if (kk + 1 < nK) {
            const int k0 = k0base + ((kk + 1) << 5);
            const int nb = (kk + 1) & 1;
            cp16(&A[(size_t)(m0 + r1) * DINNER + k0 + kc1], &As[nb][tid * 8]);
            cp16(&A[(size_t)(m0 + r1 + 64) * DINNER + k0 + kc1], &As[nb][(tid + 256) * 8]);
            if (tid < XPN * 4)
                cp16(&B[(size_t)r1 * DINNER + k0 + kc1], &Bs[nb][tid * 8]);
        }
        const int cb = kk & 1;
        short8 af[2], bfm[3];
#pragma unroll
        for (int i = 0; i < 2; ++i) af[i]  = *(const short8*)&As[cb][(wm + i * 16 + l16) * 32 + quad * 8];
#pragma unroll
        for (int j = 0; j < 3; ++j) bfm[j] = *(const short8*)&Bs[cb][(j * 16 + l16) * 32 + quad * 8];
#pragma unroll
        for (int i = 0; i < 2; ++i)
#pragma unroll
            for (int j = 0; j < 3; ++j)
                acc[i][j] = __builtin_amdgcn_mfma_f32_16x16x32_bf16(af[i], bfm[j], acc[i][j], 0, 0, 0);
    }
    float* pp = ppart + (size_t)blockIdx.y * TOK * XPN;
#pragma unroll
    for (int i = 0; i < 2; ++i)
#pragma unroll
        for (int j = 0; j < 3; ++j) {
            const int col = j * 16 + l16;
#pragma unroll
            for (int r = 0; r < 4; ++r) {
                const int row = m0 + wm + i * 16 + quad * 4 + r;
                pp[(size_t)row * XPN + col] = acc[i][j][r];
            }
        }
}

// ---------------- Selective scan: chunked parallel linear recurrence ----------------
// ROUND-0/3/6 inner structure (proven no-scratch, proven fastest). Do NOT:
// (a) batch loads into register arrays (r1/r2: scratch spills), (b) LDS-stage x
// (r4: neutral), (c) fuse split-K partial sum in here (r5: regressed), (d)
// n-split x2 (r8: regressed — duplicated dt work made it VALU-bound at 70%).
// NEW (r9): dt read from dtprep_k's dtbuf (rolling scalar prefetch, like x).
__device__ __forceinline__ void load_proj_chunk(float* sp, const float* __restrict__ proj,
                                                int b, int c, int tid)
{
    const float* psrc = proj + ((size_t)b * SLEN + (size_t)c * CLEN) * 33;
    for (int i = tid; i < CLEN * 33; i += 256) {
        int s = i / 33, p = i - s * 33;
        sp[s * PROW + (p == 0 ? 32 : p - 1)] = psrc[i];
    }
}

__global__ __launch_bounds__(256) void scan_partA(
    const float* __restrict__ proj, const float* __restrict__ xin,
    const float* __restrict__ dtbuf,
    float* __restrict__ hloc, float* __restrict__ cumA_g)
{
    __shared__ __align__(16) float sp[CLEN * PROW];
    const int tid = threadIdx.x;
    const int d = blockIdx.x * 256 + tid;
    const int c = blockIdx.y, b = blockIdx.z;
    load_proj_chunk(sp, proj, b, c, tid);
    __syncthreads();
    float h[16], ca[16];
#pragma unroll
    for (int n = 0; n < 16; ++n) { h[n] = 0.f; ca[n] = 1.f; }
    const size_t rbase = ((size_t)b * SLEN + (size_t)c * CLEN) * DINNER + d;
    const float* xrow = xin + rbase;
    const float* dtrow = dtbuf + rbase;
    float xt_next = xrow[0];
    float dt_next = dtrow[0];
    for (int s = 0; s < CLEN; ++s) {
        const float xt = xt_next;
        const float dt = dt_next;
        if (s + 1 < CLEN) {
            xt_next = xrow[(size_t)(s + 1) * DINNER];
            dt_next = dtrow[(size_t)(s + 1) * DINNER];
        }
        const float* row = &sp[s * PROW];
        const float u = dt * xt;
#pragma unroll
        for (int n = 0; n < 16; ++n) {
            const float a = fmaf(dt, -(float)(n + 1), 1.f);
            h[n] = fmaf(h[n], a, u * row[n]);
            ca[n] *= a;
        }
    }
    const size_t base = (((size_t)b * NCHUNK + c) * 16) * DINNER + d;
#pragma unroll
    for (int n = 0; n < 16; ++n) {
        hloc[base + (size_t)n * DINNER] = h[n];
        cumA_g[base + (size_t)n * DINNER] = ca[n];
    }
}

__global__ __launch_bounds__(256) void scan_combine(
    const float* __restrict__ hloc, const float* __restrict__ cumA_g,
    float* __restrict__ hin)
{
    const int idx = blockIdx.x * 256 + threadIdx.x;  // (b, n, d)
    const int d = idx & (DINNER - 1);
    const int n = (idx >> 11) & 15;
    const int b = idx >> 15;
    float h = 0.f;
    for (int c = 0; c < NCHUNK; ++c) {
        const size_t off = (((size_t)b * NCHUNK + c) * 16 + n) * DINNER + d;
        hin[off] = h;
        h = fmaf(cumA_g[off], h, hloc[off]);
    }
}

__global__ __launch_bounds__(256) void scan_partC(
    const float* __restrict__ proj, const float* __restrict__ xin,
    const float* __restrict__ dtbuf,
    const float* __restrict__ Dp, int layer,
    const float* __restrict__ hin, float* __restrict__ y)
{
    __shared__ __align__(16) float sp[CLEN * PROW];
    const int tid = threadIdx.x;
    const int d = blockIdx.x * 256 + tid;
    const int c = blockIdx.y, b = blockIdx.z;
    load_proj_chunk(sp, proj, b, c, tid);
    const float Dd = Dp[(size_t)layer * DINNER + d];
    __syncthreads();
    float h[16];
    const size_t base = (((size_t)b * NCHUNK + c) * 16) * DINNER + d;
#pragma unroll
    for (int n = 0; n < 16; ++n) h[n] = hin[base + (size_t)n * DINNER];
    const size_t rbase = ((size_t)b * SLEN + (size_t)c * CLEN) * DINNER + d;
    const float* xrow = xin + rbase;
    const float* dtrow = dtbuf + rbase;
    float* yrow = y + rbase;
    float xt_next = xrow[0];
    float dt_next = dtrow[0];
    for (int s = 0; s < CLEN; ++s) {
        const float xt = xt_next;
        const float dt = dt_next;
        if (s + 1 < CLEN) {
            xt_next = xrow[(size_t)(s + 1) * DINNER];
            dt_next = dtrow[(size_t)(s + 1) * DINNER];
        }
        const float* row = &sp[s * PROW];
        const float u = dt * xt;
        float yp = 0.f;
#pragma unroll
        for (int n = 0; n < 16; ++n) {
            const float a = fmaf(dt, -(float)(n + 1), 1.f);
            h[n] = fmaf(h[n], a, u * row[n]);
            yp = fmaf(h[n], row[16 + n], yp);
        }
        yrow[(size_t)s * DINNER] = yp + xt * Dd;
    }
}

extern "C" void kernel_launch(void* const* d_in, const int* in_sizes, int n_in,
                              void* d_out, int out_size, void* d_ws, size_t ws_size,
                              hipStream_t stream)
{
    (void)in_sizes; (void)n_in; (void)out_size;
    const float* hs   = (const float*)d_in[0];
    const float* ing  = (const float*)d_in[1];
    const float* inb  = (const float*)d_in[2];
    const float* lng  = (const float*)d_in[3];
    const float* lnb  = (const float*)d_in[4];
    const float* ipw  = (const float*)d_in[5];
    const float* cw   = (const float*)d_in[6];
    const float* cbp  = (const float*)d_in[7];
    const float* xpw  = (const float*)d_in[8];
    const float* dtw  = (const float*)d_in[9];
    const float* dtb  = (const float*)d_in[10];
    const float* Dp   = (const float*)d_in[11];
    const float* mlg  = (const float*)d_in[12];
    const float* mlb  = (const float*)d_in[13];
    const float* opw  = (const float*)d_in[14];
    const float* w1f  = (const float*)d_in[15];
    const float* b1f  = (const float*)d_in[16];
    const float* w2f  = (const float*)d_in[17];
    const float* b2f  = (const float*)d_in[18];

    // ---- workspace carve ----
    char* p = (char*)d_ws;
    float* x   = (float*)p; p += (size_t)TOK * HDIM * 4;
    float* xr  = (float*)p; p += (size_t)TOK * 2 * DINNER * 4;
    float* c2  = (float*)p; p += (size_t)TOK * DINNER * 4;
    float* yb  = (float*)p; p += (size_t)TOK * DINNER * 4;
    float* dtbuf=(float*)p; p += (size_t)TOK * DINNER * 4;                   // 16.8 MB
    float* proj= (float*)p; p += ((size_t)TOK * 33 * 4 + 255) & ~(size_t)255;
    float* hin = (float*)p; p += (size_t)NB * NCHUNK * 16 * DINNER * 4;      // 8.4 MB
    float* ppart=(float*)p; p += (size_t)XSPLIT * TOK * XPN * 4;             // 3.1 MB
    __hip_bfloat16* xn  = (__hip_bfloat16*)p; p += (size_t)TOK * HDIM * 2;
    __hip_bfloat16* y2  = (__hip_bfloat16*)p; p += (size_t)TOK * DINNER * 2;
    __hip_bfloat16* c2b = (__hip_bfloat16*)p; p += (size_t)TOK * DINNER * 2; // 8 MB
    __hip_bfloat16* wx  = (__hip_bfloat16*)p; p += (size_t)LNUM * XPN * DINNER * 2;
    __hip_bfloat16* t1 = (__hip_bfloat16*)xr;  // alias: xr dead after layer loop
    float* hloc = yb;                           // alias: yb region, dead before partC writes
    float* cumA = yb + (size_t)NB * NCHUNK * 16 * DINNER;
    float* opart = c2;                          // alias: c2 dead after scan_partC

    const size_t IPL = (size_t)2 * DINNER * HDIM;
    const size_t OPL = (size_t)HDIM * DINNER;
    const size_t MLPW = (size_t)HDIM * HDIM;

    size_t used = (size_t)(p - (char*)d_ws);
    const bool bulk = (used + (IPL * LNUM + OPL * LNUM + 2 * MLPW) * 2) <= ws_size;

    __hip_bfloat16 *wi[LNUM], *wo[LNUM], *w1, *w2;
    if (bulk) {
        for (int l = 0; l < LNUM; ++l) { wi[l] = (__hip_bfloat16*)p; p += IPL * 2; }
        for (int l = 0; l < LNUM; ++l) { wo[l] = (__hip_bfloat16*)p; p += OPL * 2; }
        w1 = (__hip_bfloat16*)p; p += MLPW * 2;
        w2 = (__hip_bfloat16*)p; p += MLPW * 2;
    } else {
        __hip_bfloat16* slotA = (__hip_bfloat16*)p; p += IPL * 2;
        __hip_bfloat16* slotB = (__hip_bfloat16*)p; p += OPL * 2;
        for (int l = 0; l < LNUM; ++l) { wi[l] = slotA; wo[l] = slotB; }
        w1 = slotA; w2 = slotB;
    }

    // x_proj weights: convert + zero-pad to [L, 48, DINNER]
    cvtwx_k<<<(LNUM * XPN * DINNER / 4 + 255) / 256, 256, 0, stream>>>(xpw, wx);

    if (bulk) {
        cvt_k<<<(int)(IPL * LNUM / 4 / 256), 256, 0, stream>>>(ipw, wi[0], (int)(IPL * LNUM / 4));
        cvt_k<<<(int)(OPL * LNUM / 4 / 256), 256, 0, stream>>>(opw, wo[0], (int)(OPL * LNUM / 4));
        cvt_k<<<(int)(MLPW / 4 / 256), 256, 0, stream>>>(w1f, w1, (int)(MLPW / 4));
        cvt_k<<<(int)(MLPW / 4 / 256), 256, 0, stream>>>(w2f, w2, (int)(MLPW / 4));
    }

    // x = layernorm(hidden_states); then xn = bf16(LN_0(x)) for layer 0
    ln_k<0, HDIM><<<TOK, 256, 0, stream>>>(hs, ing, inb, x, nullptr, nullptr, 0);
    ln_k<1, HDIM><<<TOK, 256, 0, stream>>>(x, lng, lnb, nullptr, xn, nullptr, 0);

    for (int l = 0; l < LNUM; ++l) {
        if (!bulk)
            cvt_k<<<(int)(IPL / 4 / 256), 256, 0, stream>>>(ipw + (size_t)l * IPL, wi[l], (int)(IPL / 4));
        gemm_bt<0><<<dim3(TOK / 128, (2 * DINNER) / 128), 256, 0, stream>>>(
            (const unsigned short*)xn, (const unsigned short*)wi[l],
            TOK, 2 * DINNER, HDIM, xr, nullptr, nullptr, nullptr, nullptr);

        conv2_fused<<<dim3(DINNER / 256, SLEN / CCH, NB), 256, 0, stream>>>(
            xr, 2 * DINNER, cw, cbp, l, c2, c2b);

        xproj_mfma<<<dim3(TOK / 128, XSPLIT), 256, 0, stream>>>(
            (const unsigned short*)c2b, (const unsigned short*)(wx + (size_t)l * XPN * DINNER), ppart);
        pcomb_k<<<(TOK * 33 + 255) / 256, 256, 0, stream>>>(ppart, proj);
        dtprep_k<<<(TOK * DINNER / 4 + 255) / 256, 256, 0, stream>>>(proj, dtw, dtb, l, dtbuf);

        scan_partA<<<dim3(DINNER / 256, NCHUNK, NB), 256, 0, stream>>>(
            proj, c2, dtbuf, hloc, cumA);
        scan_combine<<<(NB * 16 * DINNER) / 256, 256, 0, stream>>>(hloc, cumA, hin);
        scan_partC<<<dim3(DINNER / 256, NCHUNK, NB), 256, 0, stream>>>(
            proj, c2, dtbuf, Dp, l, hin, yb);

        ln_k<2, DINNER><<<TOK, 256, 0, stream>>>(yb, mlg + (size_t)l * DINNER, mlb + (size_t)l * DINNER,
                                                 nullptr, y2, xr + DINNER, 2 * DINNER);

        if (!bulk)
            cvt_k<<<(int)(OPL / 4 / 256), 256, 0, stream>>>(opw + (size_t)l * OPL, wo[l], (int)(OPL / 4));
        // out_proj split-K=2 -> deterministic partials (c2 is dead now)
        gemm_bt<1><<<dim3(TOK / 128, HDIM / 128, 2), 256, 0, stream>>>(
            (const unsigned short*)y2, (const unsigned short*)wo[l],
            TOK, HDIM, DINNER, opart, nullptr, nullptr, nullptr, nullptr);
        if (l + 1 < LNUM) {
            // fused: x += partials; xn = bf16(LN_{l+1}(x))
            xcomb_ln_k<<<TOK, 256, 0, stream>>>(opart, x,
                lng + (size_t)(l + 1) * HDIM, lnb + (size_t)(l + 1) * HDIM, xn);
        } else {
            // fused final: xn = bf16(x + partials)
            xcomb_cast_k<<<(TOK * HDIM / 4 + 255) / 256, 256, 0, stream>>>(
                opart, x, xn, TOK * HDIM / 4);
        }
    }

    // MLP: out = gelu(x @ op1^T + b1) @ op2^T + b2 + hidden_states
    if (!bulk) {
        cvt_k<<<(int)(MLPW / 4 / 256), 256, 0, stream>>>(w1f, w1, (int)(MLPW / 4));
        cvt_k<<<(int)(MLPW / 4 / 256), 256, 0, stream>>>(w2f, w2, (int)(MLPW / 4));
    }
    gemm_bt<2><<<dim3(TOK / 128, HDIM / 128), 256, 0, stream>>>(
        (const unsigned short*)xn, (const unsigned short*)w1,
        TOK, HDIM, HDIM, nullptr, t1, b1f, nullptr, nullptr);
    gemm_bt<3><<<dim3(TOK / 128, HDIM / 128), 256, 0, stream>>>(
        (const unsigned short*)t1, (const unsigned short*)w2,
        TOK, HDIM, HDIM, nullptr, nullptr, b2f, hs, (float*)d_out);
}